// Round 5
// baseline (242.580 us; speedup 1.0000x reference)
//
#include <hip/hip_runtime.h>

#define BB 32
#define FF 8
#define NN 131072
#define CC 16

constexpr float DELTA_VAR  = 0.5f;
constexpr float DELTA_DIST = 1.5f;
constexpr float ALPHA = 1.0f, BETA = 1.0f, GAMMA = 0.001f;

// ws float layout (atomic accumulators zeroed per launch)
#define WS_SUMS  64        // 4096: b*128 + f*16 + c
#define WS_CNTF  4160      // 512:  b*16 + c
#define WS_VAR   4672      // 1
// zero region: floats [0, 4673)

#define CHUNKS 64
#define POINTS (NN / CHUNKS)   // 2048

// ---------------- Pass 1: per-(b,c) sums + counts ----------------
// 8 feature-groups x 32 threads; each thread owns a private 16-slot LDS row
// (stride 17). Accumulate via hardware ds_add_f32 (atomicAdd, result unused):
// fire-and-forget, no software RMW chain, no same-address contention.
__global__ __launch_bounds__(256) void k_sums(const float* __restrict__ x,
                                              const int* __restrict__ tgt,
                                              float* __restrict__ ws) {
    __shared__ float priv[256 * 17];   // 17.4 KB
    __shared__ float cpriv[32 * 17];   //  2.2 KB counts (f==0 group)
    const int tid = threadIdx.x;
#pragma unroll
    for (int i = 0; i < 16; ++i) priv[tid * 17 + i] = 0.f;
    if (tid < 32) {
#pragma unroll
        for (int i = 0; i < 16; ++i) cpriv[tid * 17 + i] = 0.f;
    }
    __syncthreads();

    const int b  = blockIdx.y;
    const int f  = tid >> 5;          // feature group 0..7
    const int g  = tid & 31;          // lane-in-group
    const int n0 = blockIdx.x * POINTS;
    const float* __restrict__ xf = x + (size_t)b * FF * NN + (size_t)f * NN;
    const int*   __restrict__ tb = tgt + (size_t)b * NN;
    float* const pr = &priv[tid * 17];
    float* const cp = &cpriv[g * 17];

#pragma unroll 2
    for (int k = 0; k < POINTS / 128; ++k) {
        const int n = n0 + k * 128 + g * 4;
        const int4   t4 = *reinterpret_cast<const int4*>(tb + n);
        const float4 v  = *reinterpret_cast<const float4*>(xf + n);
        atomicAdd(&pr[t4.x], v.x);
        atomicAdd(&pr[t4.y], v.y);
        atomicAdd(&pr[t4.z], v.z);
        atomicAdd(&pr[t4.w], v.w);
        if (f == 0) {
            atomicAdd(&cp[t4.x], 1.f);
            atomicAdd(&cp[t4.y], 1.f);
            atomicAdd(&cp[t4.z], 1.f);
            atomicAdd(&cp[t4.w], 1.f);
        }
    }
    __syncthreads();

    // block reduce: 128 threads cover (f,c); 16 threads cover counts
    if (tid < 128) {
        const int rf = tid >> 4, rc = tid & 15;
        float s = 0.f;
#pragma unroll
        for (int gg = 0; gg < 32; ++gg) s += priv[(rf * 32 + gg) * 17 + rc];
        atomicAdd(&ws[WS_SUMS + b * 128 + rf * 16 + rc], s);
    } else if (tid < 144) {
        const int rc = tid - 128;
        float s = 0.f;
#pragma unroll
        for (int gg = 0; gg < 32; ++gg) s += cpriv[gg * 17 + rc];
        atomicAdd(&ws[WS_CNTF + b * 16 + rc], s);
    }
}

// ---------------- Pass 2: variance term (derives means in prologue) ---------
__global__ __launch_bounds__(256) void k_var(const float* __restrict__ x,
                                             const int* __restrict__ tgt,
                                             float* __restrict__ ws) {
    __shared__ float smean[CC * 9];   // (9c+f)%32 distinct per c -> conflict-light
    __shared__ float sinv[CC];
    const int tid = threadIdx.x;
    const int b = blockIdx.y;

    if (tid < CC) {
        const float cnt = ws[WS_CNTF + b * 16 + tid];
        sinv[tid] = cnt > 0.f ? 1.f / cnt : 0.f;
    }
    __syncthreads();
    if (tid < 128) {
        const int f = tid >> 4, c = tid & 15;
        smean[c * 9 + f] = ws[WS_SUMS + b * 128 + tid] * sinv[c];
    }
    __syncthreads();

    const int n0 = blockIdx.x * POINTS;
    const float* __restrict__ xb = x + (size_t)b * FF * NN;
    const int*   __restrict__ tb = tgt + (size_t)b * NN;

    float acc = 0.f;
    for (int n = n0 + tid * 4; n < n0 + POINTS; n += 256 * 4) {
        const int4 t4 = *reinterpret_cast<const int4*>(tb + n);
        float s0 = 0.f, s1 = 0.f, s2 = 0.f, s3 = 0.f;
#pragma unroll
        for (int f = 0; f < FF; ++f) {
            const float4 v = *reinterpret_cast<const float4*>(xb + (size_t)f * NN + n);
            s0 += fabsf(v.x - smean[t4.x * 9 + f]);
            s1 += fabsf(v.y - smean[t4.y * 9 + f]);
            s2 += fabsf(v.z - smean[t4.z * 9 + f]);
            s3 += fabsf(v.w - smean[t4.w * 9 + f]);
        }
        float h;
        h = fmaxf(s0 - DELTA_VAR, 0.f); acc += h * h * sinv[t4.x];
        h = fmaxf(s1 - DELTA_VAR, 0.f); acc += h * h * sinv[t4.y];
        h = fmaxf(s2 - DELTA_VAR, 0.f); acc += h * h * sinv[t4.z];
        h = fmaxf(s3 - DELTA_VAR, 0.f); acc += h * h * sinv[t4.w];
    }

#pragma unroll
    for (int off = 32; off > 0; off >>= 1) acc += __shfl_down(acc, off, 64);
    __shared__ float wsum[4];
    const int wave = tid >> 6, lane = tid & 63;
    if (lane == 0) wsum[wave] = acc;
    __syncthreads();
    if (tid == 0) atomicAdd(&ws[WS_VAR], wsum[0] + wsum[1] + wsum[2] + wsum[3]);
}

// ---------------- Final: means -> dist + reg, combine with var --------------
__global__ __launch_bounds__(512) void k_final(const int* __restrict__ tgt,
                                               const float* __restrict__ ws,
                                               float* __restrict__ out) {
    __shared__ float smeans[BB * CC * FF];  // 16 KB
    __shared__ int   st[BB * CC];
    __shared__ float red[512];

    const int tid = threadIdx.x;
    const int b = tid >> 4;
    const int c = tid & 15;

    const float cnt = ws[WS_CNTF + b * 16 + c];
    const float inv = cnt > 0.f ? 1.f / cnt : 0.f;
    float l1 = 0.f;
#pragma unroll
    for (int f = 0; f < FF; ++f) {
        const float m = ws[WS_SUMS + b * 128 + f * 16 + c] * inv;
        smeans[(b * CC + c) * FF + f] = m;
        l1 += fabsf(m);
    }
    st[b * CC + c] = tgt[(size_t)b * NN + c];   // label of point index c (<16)

    float contrib = (GAMMA / (float)(CC * BB)) * l1;   // reg, pre-scaled
    __syncthreads();

    // dist term: mc[b][i] = means[b][ target[b][i] ], i = c here
    const int ti = st[b * CC + c];
    float mi[FF];
#pragma unroll
    for (int f = 0; f < FF; ++f) mi[f] = smeans[(b * CC + ti) * FF + f];

    float dsum = 0.f;
    for (int j = 0; j < CC; ++j) {
        const int tj = st[b * CC + j];
        float d = 0.f;
#pragma unroll
        for (int f = 0; f < FF; ++f) d += fabsf(mi[f] - smeans[(b * CC + tj) * FF + f]);
        if (j != c) {
            const float h = 2.f * DELTA_DIST - d;
            if (h > 0.f) dsum += h * h;
        }
    }
    contrib += (BETA / (float)(CC * (CC - 1) * BB)) * dsum;

    red[tid] = contrib;
    __syncthreads();
    for (int s = 256; s > 0; s >>= 1) {
        if (tid < s) red[tid] += red[tid + s];
        __syncthreads();
    }
    if (tid == 0) out[0] = ALPHA * ws[WS_VAR] / (float)BB + red[0];
}

extern "C" void kernel_launch(void* const* d_in, const int* in_sizes, int n_in,
                              void* d_out, int out_size, void* d_ws, size_t ws_size,
                              hipStream_t stream) {
    const float* x  = (const float*)d_in[0];
    const int* tgt  = (const int*)d_in[1];
    float* out = (float*)d_out;
    float* ws  = (float*)d_ws;

    // zero atomic accumulators (sums, counts, var)
    hipMemsetAsync(ws, 0, (size_t)4673 * sizeof(float), stream);

    dim3 grid(CHUNKS, BB);
    k_sums<<<grid, 256, 0, stream>>>(x, tgt, ws);
    k_var <<<grid, 256, 0, stream>>>(x, tgt, ws);
    k_final<<<1, 512, 0, stream>>>(tgt, ws, out);
}

// Round 6
// 61.257 us; speedup vs baseline: 3.9600x; 3.9600x over previous
//
#include <hip/hip_runtime.h>

#define BB 32
#define FF 8
#define NN 131072
#define CC 16

#define CHUNKS 64
#define POINTS (NN / CHUNKS)   // 2048
#define NBLK   (CHUNKS * BB)   // 2048

constexpr float DELTA_VAR  = 0.5f;
constexpr float DELTA_DIST = 1.5f;
constexpr float ALPHA = 1.0f, BETA = 1.0f, GAMMA = 0.001f;

// ws float layout — every slot is written before it is read each launch,
// so NO zeroing/memset is needed (0xAA poison is harmless).
#define PSLOT    160                       // 144 used, padded
#define WS_PART  0                         // NBLK*PSLOT: blk=(b*64+ch), slot f*16+c; counts at 128+c
#define WS_VARP  (NBLK * PSLOT)            // NBLK
#define WS_MEANS (WS_VARP + NBLK)          // B*C*F: (b*16+c)*8+f

// ---------------- Pass 1: per-chunk sums + counts (software RMW, private rows)
__global__ __launch_bounds__(256) void k_sums(const float* __restrict__ x,
                                              const int* __restrict__ tgt,
                                              float* __restrict__ ws) {
    __shared__ float priv[256 * 17];   // 17.4 KB private rows, stride 17
    __shared__ float cpriv[32 * 17];   //  2.2 KB counts (f==0 group)
    const int tid = threadIdx.x;
#pragma unroll
    for (int i = 0; i < 16; ++i) priv[tid * 17 + i] = 0.f;
    if (tid < 32) {
#pragma unroll
        for (int i = 0; i < 16; ++i) cpriv[tid * 17 + i] = 0.f;
    }
    __syncthreads();

    const int b  = blockIdx.y;
    const int ch = blockIdx.x;
    const int f  = tid >> 5;          // feature group 0..7
    const int g  = tid & 31;          // lane-in-group
    const int n0 = ch * POINTS;
    const float* __restrict__ xf = x + (size_t)b * FF * NN + (size_t)f * NN;
    const int*   __restrict__ tb = tgt + (size_t)b * NN;
    const int base  = tid * 17;
    const int cbase = g * 17;

#pragma unroll 2
    for (int k = 0; k < POINTS / 128; ++k) {
        const int n = n0 + k * 128 + g * 4;
        const int4   t4 = *reinterpret_cast<const int4*>(tb + n);
        const float4 v  = *reinterpret_cast<const float4*>(xf + n);
        priv[base + t4.x] += v.x;
        priv[base + t4.y] += v.y;
        priv[base + t4.z] += v.z;
        priv[base + t4.w] += v.w;
        if (f == 0) {
            cpriv[cbase + t4.x] += 1.f;
            cpriv[cbase + t4.y] += 1.f;
            cpriv[cbase + t4.z] += 1.f;
            cpriv[cbase + t4.w] += 1.f;
        }
    }
    __syncthreads();

    // block reduce -> per-block partial slots (plain stores, no atomics)
    float* const part = &ws[WS_PART + (size_t)(b * CHUNKS + ch) * PSLOT];
    if (tid < 128) {
        // slot = f*16 + c  == tid with rf=tid>>4, rc=tid&15
        const int rf = tid >> 4, rc = tid & 15;
        float s = 0.f;
#pragma unroll
        for (int gg = 0; gg < 32; ++gg) s += priv[(rf * 32 + gg) * 17 + rc];
        part[tid] = s;
    } else if (tid < 144) {
        const int rc = tid - 128;
        float s = 0.f;
#pragma unroll
        for (int gg = 0; gg < 32; ++gg) s += cpriv[gg * 17 + rc];
        part[tid] = s;
    }
}

// ---------------- Pass 2: variance term; prologue derives means from partials
__global__ __launch_bounds__(256) void k_var(const float* __restrict__ x,
                                             const int* __restrict__ tgt,
                                             float* __restrict__ ws) {
    __shared__ float sred[144];
    __shared__ float smf[CC * 12];     // float4-pair rows at stride 3 float4s
    __shared__ float sinv[CC];
    __shared__ float wsum[4];

    const int tid = threadIdx.x;
    const int b   = blockIdx.y;
    const int ch  = blockIdx.x;

    if (tid < 144) {
        const float* p = &ws[WS_PART + (size_t)b * CHUNKS * PSLOT + tid];
        float s = 0.f;
#pragma unroll 8
        for (int c2 = 0; c2 < CHUNKS; ++c2) s += p[(size_t)c2 * PSLOT];
        sred[tid] = s;
    }
    __syncthreads();
    if (tid < CC) {
        const float cnt = sred[128 + tid];
        sinv[tid] = cnt > 0.f ? 1.f / cnt : 0.f;
    }
    __syncthreads();
    if (tid < 128) {
        const int f = tid >> 4, c = tid & 15;
        const float m = sred[tid] * sinv[c];
        smf[c * 12 + f] = m;
        if (ch == 0) ws[WS_MEANS + ((size_t)b * CC + c) * FF + f] = m;
    }
    __syncthreads();

    const float4* sm4 = reinterpret_cast<const float4*>(smf);
    const int n0 = ch * POINTS;
    const float* __restrict__ xb = x + (size_t)b * FF * NN;
    const int*   __restrict__ tb = tgt + (size_t)b * NN;

    float acc = 0.f;
#pragma unroll
    for (int it = 0; it < 2; ++it) {
        const int n = n0 + tid * 4 + it * 1024;
        const int4 t4 = *reinterpret_cast<const int4*>(tb + n);
        const float4 A0 = sm4[3 * t4.x], B0 = sm4[3 * t4.x + 1];
        const float4 A1 = sm4[3 * t4.y], B1 = sm4[3 * t4.y + 1];
        const float4 A2 = sm4[3 * t4.z], B2 = sm4[3 * t4.z + 1];
        const float4 A3 = sm4[3 * t4.w], B3 = sm4[3 * t4.w + 1];
        float s0, s1, s2, s3;
        {
            const float4 v = *reinterpret_cast<const float4*>(xb + 0 * NN + n);
            s0 = fabsf(v.x - A0.x); s1 = fabsf(v.y - A1.x);
            s2 = fabsf(v.z - A2.x); s3 = fabsf(v.w - A3.x);
        }
        {
            const float4 v = *reinterpret_cast<const float4*>(xb + 1 * NN + n);
            s0 += fabsf(v.x - A0.y); s1 += fabsf(v.y - A1.y);
            s2 += fabsf(v.z - A2.y); s3 += fabsf(v.w - A3.y);
        }
        {
            const float4 v = *reinterpret_cast<const float4*>(xb + 2 * NN + n);
            s0 += fabsf(v.x - A0.z); s1 += fabsf(v.y - A1.z);
            s2 += fabsf(v.z - A2.z); s3 += fabsf(v.w - A3.z);
        }
        {
            const float4 v = *reinterpret_cast<const float4*>(xb + 3 * NN + n);
            s0 += fabsf(v.x - A0.w); s1 += fabsf(v.y - A1.w);
            s2 += fabsf(v.z - A2.w); s3 += fabsf(v.w - A3.w);
        }
        {
            const float4 v = *reinterpret_cast<const float4*>(xb + 4 * NN + n);
            s0 += fabsf(v.x - B0.x); s1 += fabsf(v.y - B1.x);
            s2 += fabsf(v.z - B2.x); s3 += fabsf(v.w - B3.x);
        }
        {
            const float4 v = *reinterpret_cast<const float4*>(xb + 5 * NN + n);
            s0 += fabsf(v.x - B0.y); s1 += fabsf(v.y - B1.y);
            s2 += fabsf(v.z - B2.y); s3 += fabsf(v.w - B3.y);
        }
        {
            const float4 v = *reinterpret_cast<const float4*>(xb + 6 * NN + n);
            s0 += fabsf(v.x - B0.z); s1 += fabsf(v.y - B1.z);
            s2 += fabsf(v.z - B2.z); s3 += fabsf(v.w - B3.z);
        }
        {
            const float4 v = *reinterpret_cast<const float4*>(xb + 7 * NN + n);
            s0 += fabsf(v.x - B0.w); s1 += fabsf(v.y - B1.w);
            s2 += fabsf(v.z - B2.w); s3 += fabsf(v.w - B3.w);
        }
        float h;
        h = fmaxf(s0 - DELTA_VAR, 0.f); acc += h * h * sinv[t4.x];
        h = fmaxf(s1 - DELTA_VAR, 0.f); acc += h * h * sinv[t4.y];
        h = fmaxf(s2 - DELTA_VAR, 0.f); acc += h * h * sinv[t4.z];
        h = fmaxf(s3 - DELTA_VAR, 0.f); acc += h * h * sinv[t4.w];
    }

#pragma unroll
    for (int off = 32; off > 0; off >>= 1) acc += __shfl_down(acc, off, 64);
    if ((tid & 63) == 0) wsum[tid >> 6] = acc;
    __syncthreads();
    if (tid == 0) ws[WS_VARP + b * CHUNKS + ch] = wsum[0] + wsum[1] + wsum[2] + wsum[3];
}

// ---------------- Final: dist + reg + var reduce -> out[0] ------------------
__global__ __launch_bounds__(512) void k_final(const int* __restrict__ tgt,
                                               const float* __restrict__ ws,
                                               float* __restrict__ out) {
    __shared__ float smeans[BB * CC * FF];  // 16 KB
    __shared__ int   st[BB * CC];
    __shared__ float red[512];

    const int tid = threadIdx.x;
    const int b = tid >> 4;
    const int c = tid & 15;

    float l1 = 0.f;
#pragma unroll
    for (int f = 0; f < FF; ++f) {
        const float m = ws[WS_MEANS + ((size_t)b * CC + c) * FF + f];
        smeans[(b * CC + c) * FF + f] = m;
        l1 += fabsf(m);
    }
    st[b * CC + c] = tgt[(size_t)b * NN + c];   // label of point index c (<16)

    float varp = 0.f;
#pragma unroll
    for (int i = 0; i < NBLK / 512; ++i) varp += ws[WS_VARP + i * 512 + tid];

    float contrib = (GAMMA / (float)(CC * BB)) * l1 + (ALPHA / (float)BB) * varp;
    __syncthreads();

    // dist term: mc[b][i] = means[b][ target[b][i] ], i = c here
    const int ti = st[b * CC + c];
    float mi[FF];
#pragma unroll
    for (int f = 0; f < FF; ++f) mi[f] = smeans[(b * CC + ti) * FF + f];

    float dsum = 0.f;
    for (int j = 0; j < CC; ++j) {
        const int tj = st[b * CC + j];
        float d = 0.f;
#pragma unroll
        for (int f = 0; f < FF; ++f) d += fabsf(mi[f] - smeans[(b * CC + tj) * FF + f]);
        if (j != c) {
            const float h = 2.f * DELTA_DIST - d;
            if (h > 0.f) dsum += h * h;
        }
    }
    contrib += (BETA / (float)(CC * (CC - 1) * BB)) * dsum;

    red[tid] = contrib;
    __syncthreads();
    for (int s = 256; s > 0; s >>= 1) {
        if (tid < s) red[tid] += red[tid + s];
        __syncthreads();
    }
    if (tid == 0) out[0] = red[0];
}

extern "C" void kernel_launch(void* const* d_in, const int* in_sizes, int n_in,
                              void* d_out, int out_size, void* d_ws, size_t ws_size,
                              hipStream_t stream) {
    const float* x  = (const float*)d_in[0];
    const int* tgt  = (const int*)d_in[1];
    float* out = (float*)d_out;
    float* ws  = (float*)d_ws;

    dim3 grid(CHUNKS, BB);
    k_sums<<<grid, 256, 0, stream>>>(x, tgt, ws);
    k_var <<<grid, 256, 0, stream>>>(x, tgt, ws);
    k_final<<<1, 512, 0, stream>>>(tgt, ws, out);
}